// Round 10
// baseline (2096.580 us; speedup 1.0000x reference)
//
#include <hip/hip_runtime.h>
#include <hip/hip_bf16.h>
#include <stdint.h>

#define T_STEPS 512
#define BATCH   64
#define HID     512
#define DIN     512
#define G4      2048   // 4*HID
// blocked h layout: [t][j=64][gq=4][b=16][h=8] ushorts; per-t stride:
#define HBLK_T  32768  // 64*4*16*8
#define SENT8   0xFFFFFFFFFFFFFFFFull   // 4x bf16 0xFFFF (-NaN): unreachable for finite h

typedef __attribute__((ext_vector_type(8))) short bf16x8;
typedef __attribute__((ext_vector_type(4))) float f32x4;
typedef __attribute__((ext_vector_type(4))) unsigned short us4;
typedef unsigned long long ull;

#define AGLD(p) __hip_atomic_load((p), __ATOMIC_RELAXED, __HIP_MEMORY_SCOPE_AGENT)
#define AGST(p, v) __hip_atomic_store((p), (v), __ATOMIC_RELAXED, __HIP_MEMORY_SCOPE_AGENT)
#define WGLD(p) __hip_atomic_load((p), __ATOMIC_RELAXED, __HIP_MEMORY_SCOPE_WORKGROUP)
#define WGST(p, v) __hip_atomic_store((p), (v), __ATOMIC_RELAXED, __HIP_MEMORY_SCOPE_WORKGROUP)

static __device__ __forceinline__ unsigned short f2bf(float f) {
  union { float f; unsigned u; } v; v.f = f;
  unsigned r = v.u + 0x7FFFu + ((v.u >> 16) & 1u);  // round-to-nearest-even
  return (unsigned short)(r >> 16);
}
static __device__ __forceinline__ float bf2f(unsigned short s) {
  union { unsigned u; float f; } v; v.u = ((unsigned)s) << 16;
  return v.f;
}
static __device__ __forceinline__ float sigf(float x) { return 1.f / (1.f + __expf(-x)); }
static __device__ __forceinline__ float tanh_fast(float x) {
  x = fminf(15.f, fmaxf(-15.f, x));
  float e = __expf(2.f * x);
  return (e - 1.f) / (e + 1.f);
}

__global__ void cvt_f32_bf16(const float* __restrict__ src, unsigned short* __restrict__ dst, long n) {
  long i = (long)blockIdx.x * blockDim.x + threadIdx.x;
  long st = (long)gridDim.x * blockDim.x;
  for (; i < n; i += st) dst[i] = f2bf(src[i]);
}

// One block per timestep t: stage x[.][t][.] (64x512 -> bf16) in LDS once,
// then 4 waves sweep the 2048 gate rows (weights re-read from L2).
// xg[t][g][b] = sum_k x[b][t][k]*Wx0[g][k] + bx0[g] + bh0[g].
__global__ __launch_bounds__(256) void proj_kernel(
    const float* __restrict__ x,              // [B][T][D] f32
    const unsigned short* __restrict__ Wb,    // [2048][512] bf16
    const float* __restrict__ ba,             // bx0 [2048]
    const float* __restrict__ bb,             // bh0 [2048]
    unsigned short* __restrict__ xg) {
  __shared__ unsigned short xt[64 * 512];     // 64 KB, XOR-swizzled rows
  const int t   = blockIdx.x;
  const int tid = threadIdx.x;

  for (int i = 0; i < 16; ++i) {
    const int c    = i * 256 + tid;
    const int b    = c >> 6;
    const int col8 = c & 63;
    const float* src = x + ((long)b * T_STEPS + t) * DIN + col8 * 8;
    f32x4 v0 = *(const f32x4*)(src);
    f32x4 v1 = *(const f32x4*)(src + 4);
    union { unsigned short s[8]; bf16x8 v; } u;
    #pragma unroll
    for (int e = 0; e < 4; ++e) { u.s[e] = f2bf(v0[e]); u.s[4 + e] = f2bf(v1[e]); }
    const int byteoff = b * 1024 + ((col8 * 16) ^ ((b & 7) << 4));
    *(bf16x8*)((char*)xt + byteoff) = u.v;
  }
  __syncthreads();

  const int wv   = tid >> 6;
  const int lane = tid & 63;
  const int n16  = lane & 15;
  const int q    = lane >> 4;
  const int kof  = q * 8;

  for (int gt = 0; gt < 32; ++gt) {
    const int g0 = wv * 512 + gt * 16;
    const unsigned short* ap = Wb + (long)(g0 + n16) * DIN + kof;
    f32x4 acc[4];
    #pragma unroll
    for (int nb = 0; nb < 4; ++nb) acc[nb] = (f32x4){0.f, 0.f, 0.f, 0.f};
    #pragma unroll
    for (int kk = 0; kk < 16; ++kk) {
      bf16x8 a = *(const bf16x8*)(ap + kk * 32);
      const int colb = (kof + kk * 32) * 2;
      #pragma unroll
      for (int nb = 0; nb < 4; ++nb) {
        const int row = nb * 16 + n16;
        bf16x8 bv = *(const bf16x8*)((const char*)xt + row * 1024 + (colb ^ ((row & 7) << 4)));
        acc[nb] = __builtin_amdgcn_mfma_f32_16x16x32_bf16(a, bv, acc[nb], 0, 0, 0);
      }
    }
    const int m0 = q * 4;
    #pragma unroll
    for (int r = 0; r < 4; ++r) {
      const int g = g0 + m0 + r;
      const float bv = ba[g] + bb[g];
      long base = ((long)t * G4 + g) * BATCH + n16;
      xg[base +  0] = f2bf(acc[0][r] + bv);
      xg[base + 16] = f2bf(acc[1][r] + bv);
      xg[base + 32] = f2bf(acc[2][r] + bv);
      xg[base + 48] = f2bf(acc[3][r] + bv);
    }
  }
}

// Fused 2-layer dataflow recurrence. 256 WGs x 128 threads, 1 WG/CU.
// Operand-SWAPPED MFMAs (A=weights, B=h): D row=gate-row, col=batch, so
// lanes (n16, q<2) publish (batch, 4 hids) with ONE 8B register store —
// no LDS repack bounce on the critical chain. Sentinel-polled T-deep h
// rings (L3, agent scope); selective masked reload in all polls;
// L0->L1 LDS ring provided right after validation (overlaps L0 compute).
__global__ __launch_bounds__(128, 1) void fused_rec(
    const float* __restrict__ Wh0,            // [2048][512] f32
    const float* __restrict__ Wx1,            // [2048][512] f32
    const float* __restrict__ Wh1,            // [2048][512] f32
    const float* __restrict__ bx1, const float* __restrict__ bh1,
    const unsigned short* __restrict__ xg0,   // [T][2048][64] bf16 (bias folded)
    unsigned short* __restrict__ hseq1,       // [T][64][4][16][8] bf16, 0xFF-filled
    unsigned short* __restrict__ hseq2,       // [T][64][4][16][8] bf16, 0xFF-filled
    float* __restrict__ out,                  // [64][512]
    int T) {
  __shared__ unsigned short whl0[32 * 512];                 // 32 KB
  __shared__ unsigned short whl1[32 * 1024];                // 64 KB
  __shared__ __align__(16) unsigned short ring[2 * 64 * 128];  // 32 KB
  __shared__ int l0_wr, l1_rd;

  const int bid  = blockIdx.x;
  const int gq   = bid & 3;
  const int j    = bid >> 2;
  const int wv   = threadIdx.x >> 6;
  const int lane = threadIdx.x & 63;
  const int hidbase = j * 8;
  const int n16  = lane & 15;
  const int q    = lane >> 4;
  const int kof  = q * 8;
  const int rr0 = n16, rr1 = 16 + n16;
  const int rdbase = gq * 128 + n16 * 8;       // ushort units
  const int myblk  = (j * 4 + gq) * 128;       // ushort units
  const int rsw    = (lane & 7) << 4;          // ring XOR swizzle
  // D-row gate index base for this lane's acc rows (tile0); tile1 = +1024
  const int gofs0  = (q >> 1) * 512 + hidbase + (q & 1) * 4;

  if (threadIdx.x == 0) { l0_wr = 0; l1_rd = 0; }

  // ---- LDS weight fills (f32 -> bf16 inline, XOR-swizzled) ----
  auto cv8 = [](const float* s) -> bf16x8 {
    f32x4 a = *(const f32x4*)s, b = *(const f32x4*)(s + 4);
    union { unsigned short u[8]; bf16x8 v; } w;
    #pragma unroll
    for (int e = 0; e < 4; ++e) { w.u[e] = f2bf(a[e]); w.u[4 + e] = f2bf(b[e]); }
    return w.v;
  };
  if (wv == 0) {
    for (int r = 0; r < 32; ++r) {
      const long grow = (long)(r >> 3) * HID + hidbase + (r & 7);
      bf16x8 v = cv8(Wh0 + grow * HID + lane * 8);
      *(bf16x8*)((char*)whl0 + r * 1024 + ((lane * 16) ^ ((r & 7) << 4))) = v;
    }
  } else {
    for (int r = 0; r < 32; ++r) {
      const long grow = (long)(r >> 3) * HID + hidbase + (r & 7);
      bf16x8 va = cv8(Wx1 + grow * HID + lane * 8);
      bf16x8 vb = cv8(Wh1 + grow * HID + lane * 8);
      const int rb = r * 2048;
      *(bf16x8*)((char*)whl1 + rb + ((lane * 16) ^ ((r & 7) << 4))) = va;
      *(bf16x8*)((char*)whl1 + rb + ((1024 + lane * 16) ^ ((r & 7) << 4))) = vb;
    }
  }
  __syncthreads();  // once; the two waves decouple afterwards

  if (wv == 0) {
    // ================= layer 0 =================
    float c4[4] = {0.f, 0.f, 0.f, 0.f};
    for (int t = 0; t < T; ++t) {
      // xg pre-issue: 8 x 2B scalar loads (off-chain; hides under the poll)
      const unsigned short* xp = xg0 + ((long)t * G4 + gofs0) * BATCH + gq * 16 + n16;
      unsigned short xs0[4], xs1[4];
      #pragma unroll
      for (int r = 0; r < 4; ++r) {
        xs0[r] = xp[r * BATCH];
        xs1[r] = xp[(1024 + r) * BATCH];
      }
      ull lo[16], hi[16];
      if (t > 0) {
        const ull* hp = (const ull*)(hseq1 + (long)(t - 1) * HBLK_T + rdbase);
        #pragma unroll
        for (int kk = 0; kk < 16; ++kk) { lo[kk] = SENT8; hi[kk] = SENT8; }
        int bad;
        do {
          #pragma unroll
          for (int kk = 0; kk < 16; ++kk) {   // selective: reload only missing
            const int boff = (kk * 4 + q) * 128;
            if (lo[kk] == SENT8) lo[kk] = AGLD(hp + boff);
            if (hi[kk] == SENT8) hi[kk] = AGLD(hp + boff + 1);
          }
          bad = 0;
          #pragma unroll
          for (int kk = 0; kk < 16; ++kk)
            bad |= (lo[kk] == SENT8) | (hi[kk] == SENT8);
        } while (__any(bad));
        // ---- ring-provide slot (t-1)&1 EARLY: unblocks L1 before our MFMAs
        while (WGLD(&l1_rd) < t - 2) {}
        asm volatile("" ::: "memory");
        char* slot = (char*)ring + ((t - 1) & 1) * 16384 + lane * 256;
        #pragma unroll
        for (int kk = 0; kk < 16; ++kk) {
          union { ull qq[2]; bf16x8 v; } u; u.qq[0] = lo[kk]; u.qq[1] = hi[kk];
          *(bf16x8*)(slot + ((kk * 16) ^ rsw)) = u.v;
        }
        asm volatile("s_waitcnt lgkmcnt(0)" ::: "memory");
        if (lane == 0) WGST(&l0_wr, t);
      }
      f32x4 acc0 = {0.f,0.f,0.f,0.f}, acc1 = {0.f,0.f,0.f,0.f};
      if (t > 0) {
        #pragma unroll
        for (int kk = 0; kk < 16; ++kk) {
          union { ull qq[2]; bf16x8 v; } u; u.qq[0] = lo[kk]; u.qq[1] = hi[kk];
          const int colb = (kof + kk * 32) * 2;
          bf16x8 a0 = *(const bf16x8*)((const char*)whl0 + rr0 * 1024 + (colb ^ ((rr0 & 7) << 4)));
          bf16x8 a1 = *(const bf16x8*)((const char*)whl0 + rr1 * 1024 + (colb ^ ((rr1 & 7) << 4)));
          acc0 = __builtin_amdgcn_mfma_f32_16x16x32_bf16(a0, u.v, acc0, 0, 0, 0);  // A=W, B=h
          acc1 = __builtin_amdgcn_mfma_f32_16x16x32_bf16(a1, u.v, acc1, 0, 0, 0);
        }
      }
      #pragma unroll
      for (int r = 0; r < 4; ++r) { acc0[r] += bf2f(xs0[r]); acc1[r] += bf2f(xs1[r]); }

      f32x4 o0, o1;   // partner rows: f<->i, g<->o live at lane^32 (q^2)
      #pragma unroll
      for (int r = 0; r < 4; ++r) {
        o0[r] = __shfl_xor(acc0[r], 32, 64);
        o1[r] = __shfl_xor(acc1[r], 32, 64);
      }
      if (q < 2) {     // lane holds (batch n16, hids hidbase+q*4+r)
        us4 hb4;
        #pragma unroll
        for (int r = 0; r < 4; ++r) {
          const float fg = sigf(acc0[r]);
          const float ig = sigf(o0[r]);
          const float gg = tanh_fast(acc1[r]);
          const float og = sigf(o1[r]);
          const float cn = fg * c4[r] + ig * gg;
          c4[r] = cn;
          hb4[r] = f2bf(og * tanh_fast(cn));
        }
        union { us4 v; ull u; } pk; pk.v = hb4;
        ull* dst = (ull*)(hseq1 + (long)t * HBLK_T + myblk) + n16 * 2 + q;
        AGST(dst, pk.u);   // direct register publish: 32 x 8B = 4 full lines
      }
    }
    // ---- epilogue: provide ring slot (T-1)&1 with validated h1[T-1] ----
    {
      const ull* hp = (const ull*)(hseq1 + (long)(T - 1) * HBLK_T + rdbase);
      ull lo[16], hi[16];
      #pragma unroll
      for (int kk = 0; kk < 16; ++kk) { lo[kk] = SENT8; hi[kk] = SENT8; }
      int bad;
      do {
        #pragma unroll
        for (int kk = 0; kk < 16; ++kk) {
          const int boff = (kk * 4 + q) * 128;
          if (lo[kk] == SENT8) lo[kk] = AGLD(hp + boff);
          if (hi[kk] == SENT8) hi[kk] = AGLD(hp + boff + 1);
        }
        bad = 0;
        #pragma unroll
        for (int kk = 0; kk < 16; ++kk)
          bad |= (lo[kk] == SENT8) | (hi[kk] == SENT8);
      } while (__any(bad));
      while (WGLD(&l1_rd) < T - 2) {}
      asm volatile("" ::: "memory");
      char* slot = (char*)ring + ((T - 1) & 1) * 16384 + lane * 256;
      #pragma unroll
      for (int kk = 0; kk < 16; ++kk) {
        union { ull qq[2]; bf16x8 v; } u; u.qq[0] = lo[kk]; u.qq[1] = hi[kk];
        *(bf16x8*)(slot + ((kk * 16) ^ rsw)) = u.v;
      }
      asm volatile("s_waitcnt lgkmcnt(0)" ::: "memory");
      if (lane == 0) WGST(&l0_wr, T);
    }
  } else {
    // ================= layer 1 =================
    float c4[4] = {0.f, 0.f, 0.f, 0.f};
    float bv0[4], bv1[4];
    #pragma unroll
    for (int r = 0; r < 4; ++r) {
      bv0[r] = bx1[gofs0 + r] + bh1[gofs0 + r];
      bv1[r] = bx1[gofs0 + 1024 + r] + bh1[gofs0 + 1024 + r];
    }
    for (int t = 0; t < T; ++t) {
      // pre-issue h2[t-1] poll loads (first full round; RTT hides under partA)
      ull lb[16], hb[16];
      const ull* pb = (const ull*)(hseq2 + (long)(t - 1) * HBLK_T + rdbase);
      if (t > 0) {
        #pragma unroll
        for (int kk = 0; kk < 16; ++kk) {
          const int boff = (kk * 4 + q) * 128;
          lb[kk] = AGLD(pb + boff);
          hb[kk] = AGLD(pb + boff + 1);
        }
      }
      // ---- partA operands from the LDS ring (validated h1[t] from own L0) ----
      while (WGLD(&l0_wr) < t + 1) {}
      asm volatile("" ::: "memory");
      bf16x8 ra[16];
      const char* slot = (const char*)ring + (t & 1) * 16384 + lane * 256;
      #pragma unroll
      for (int kk = 0; kk < 16; ++kk)
        ra[kk] = *(const bf16x8*)(slot + ((kk * 16) ^ rsw));
      asm volatile("s_waitcnt lgkmcnt(0)" ::: "memory");
      __builtin_amdgcn_sched_barrier(0);
      if (lane == 0) WGST(&l1_rd, t + 1);
      // MFMA A: Wx1 * h1[t]
      f32x4 acc0 = {0.f,0.f,0.f,0.f}, acc1 = {0.f,0.f,0.f,0.f};
      #pragma unroll
      for (int kk = 0; kk < 16; ++kk) {
        const int colb = (kof + kk * 32) * 2;
        bf16x8 a0 = *(const bf16x8*)((const char*)whl1 + rr0 * 2048 + (colb ^ ((rr0 & 7) << 4)));
        bf16x8 a1 = *(const bf16x8*)((const char*)whl1 + rr1 * 2048 + (colb ^ ((rr1 & 7) << 4)));
        acc0 = __builtin_amdgcn_mfma_f32_16x16x32_bf16(a0, ra[kk], acc0, 0, 0, 0);
        acc1 = __builtin_amdgcn_mfma_f32_16x16x32_bf16(a1, ra[kk], acc1, 0, 0, 0);
      }
      // ---- partB: selective-retry pre-issued h2[t-1], then MFMA ----
      if (t > 0) {
        for (;;) {
          int bad = 0;
          #pragma unroll
          for (int kk = 0; kk < 16; ++kk) bad |= (lb[kk] == SENT8) | (hb[kk] == SENT8);
          if (!__any(bad)) break;
          #pragma unroll
          for (int kk = 0; kk < 16; ++kk) {
            const int boff = (kk * 4 + q) * 128;
            if (lb[kk] == SENT8) lb[kk] = AGLD(pb + boff);
            if (hb[kk] == SENT8) hb[kk] = AGLD(pb + boff + 1);
          }
        }
        #pragma unroll
        for (int kk = 0; kk < 16; ++kk) {
          union { ull qq[2]; bf16x8 v; } u; u.qq[0] = lb[kk]; u.qq[1] = hb[kk];
          const int colb = 1024 + (kof + kk * 32) * 2;
          bf16x8 a0 = *(const bf16x8*)((const char*)whl1 + rr0 * 2048 + (colb ^ ((rr0 & 7) << 4)));
          bf16x8 a1 = *(const bf16x8*)((const char*)whl1 + rr1 * 2048 + (colb ^ ((rr1 & 7) << 4)));
          acc0 = __builtin_amdgcn_mfma_f32_16x16x32_bf16(a0, u.v, acc0, 0, 0, 0);
          acc1 = __builtin_amdgcn_mfma_f32_16x16x32_bf16(a1, u.v, acc1, 0, 0, 0);
        }
      }
      #pragma unroll
      for (int r = 0; r < 4; ++r) { acc0[r] += bv0[r]; acc1[r] += bv1[r]; }

      f32x4 o0, o1;
      #pragma unroll
      for (int r = 0; r < 4; ++r) {
        o0[r] = __shfl_xor(acc0[r], 32, 64);
        o1[r] = __shfl_xor(acc1[r], 32, 64);
      }
      if (q < 2) {
        us4 hb4;
        #pragma unroll
        for (int r = 0; r < 4; ++r) {
          const float fg = sigf(acc0[r]);
          const float ig = sigf(o0[r]);
          const float gg = tanh_fast(acc1[r]);
          const float og = sigf(o1[r]);
          const float cn = fg * c4[r] + ig * gg;
          c4[r] = cn;
          const float h = og * tanh_fast(cn);
          hb4[r] = f2bf(h);
          if (t == T - 1)
            out[(long)(gq * 16 + n16) * HID + hidbase + q * 4 + r] = h;
        }
        union { us4 v; ull u; } pk; pk.v = hb4;
        ull* dst = (ull*)(hseq2 + (long)t * HBLK_T + myblk) + n16 * 2 + q;
        AGST(dst, pk.u);
      }
    }
  }
}

extern "C" void kernel_launch(void* const* d_in, const int* in_sizes, int n_in,
                              void* d_out, int out_size, void* d_ws, size_t ws_size,
                              hipStream_t stream) {
  const float* x   = (const float*)d_in[0];
  const float* Wx0 = (const float*)d_in[1];
  const float* bx0 = (const float*)d_in[2];
  const float* Wh0 = (const float*)d_in[3];
  const float* bh0 = (const float*)d_in[4];
  const float* Wx1 = (const float*)d_in[5];
  const float* bx1 = (const float*)d_in[6];
  const float* Wh1 = (const float*)d_in[7];
  const float* bh1 = (const float*)d_in[8];

  char* ws = (char*)d_ws;
  size_t off = 0;
  auto alloc = [&](size_t bytes) -> char* {
    char* p = ws + off; off += (bytes + 255) & ~(size_t)255; return p;
  };
  unsigned short* xg    = (unsigned short*)alloc((size_t)T_STEPS * G4 * BATCH * 2);  // 128 MiB
  unsigned short* hseq1 = (unsigned short*)alloc((size_t)T_STEPS * HBLK_T * 2);      // 32 MiB
  unsigned short* hseq2 = (unsigned short*)alloc((size_t)T_STEPS * HBLK_T * 2);      // 32 MiB
  unsigned short* Wx0b  = (unsigned short*)alloc((size_t)G4 * DIN * 2);              // 2 MiB

  // sentinel-fill the h rings (0xFF bytes = bf16 -NaN, unreachable for real h)
  hipMemsetAsync(hseq1, 0xFF, (size_t)T_STEPS * HBLK_T * 2, stream);
  hipMemsetAsync(hseq2, 0xFF, (size_t)T_STEPS * HBLK_T * 2, stream);

  cvt_f32_bf16<<<1024, 256, 0, stream>>>(Wx0, Wx0b, (long)G4 * DIN);

  // layer-0 input projections: one block per timestep, x staged+converted in LDS
  proj_kernel<<<T_STEPS, 256, 0, stream>>>(x, Wx0b, bx0, bh0, xg);
  // fused dataflow 2-layer recurrence with L0->L1 LDS ring
  fused_rec<<<256, 128, 0, stream>>>(Wh0, Wx1, Wh1, bx1, bh1,
                                     xg, hseq1, hseq2, (float*)d_out, T_STEPS);
}

// Round 13
// 2005.232 us; speedup vs baseline: 1.0456x; 1.0456x over previous
//
#include <hip/hip_runtime.h>
#include <hip/hip_bf16.h>
#include <stdint.h>

#define T_STEPS 512
#define BATCH   64
#define HID     512
#define DIN     512
#define G4      2048   // 4*HID
// blocked h layout: [t][j=64][gq=4][b=16][h=8] ushorts; per-t stride:
#define HBLK_T  32768  // 64*4*16*8
#define SENT8   0xFFFFFFFFFFFFFFFFull   // 4x bf16 0xFFFF (-NaN): unreachable for finite h

typedef __attribute__((ext_vector_type(8))) short bf16x8;
typedef __attribute__((ext_vector_type(4))) float f32x4;
typedef __attribute__((ext_vector_type(4))) unsigned short us4;
typedef unsigned long long ull;

#define AGLD(p) __hip_atomic_load((p), __ATOMIC_RELAXED, __HIP_MEMORY_SCOPE_AGENT)
#define AGST(p, v) __hip_atomic_store((p), (v), __ATOMIC_RELAXED, __HIP_MEMORY_SCOPE_AGENT)

static __device__ __forceinline__ unsigned short f2bf(float f) {
  union { float f; unsigned u; } v; v.f = f;
  unsigned r = v.u + 0x7FFFu + ((v.u >> 16) & 1u);  // round-to-nearest-even
  return (unsigned short)(r >> 16);
}
static __device__ __forceinline__ float bf2f(unsigned short s) {
  union { unsigned u; float f; } v; v.u = ((unsigned)s) << 16;
  return v.f;
}
static __device__ __forceinline__ float sigf(float x) { return 1.f / (1.f + __expf(-x)); }
static __device__ __forceinline__ float tanh_fast(float x) {
  x = fminf(15.f, fmaxf(-15.f, x));
  float e = __expf(2.f * x);
  return (e - 1.f) / (e + 1.f);
}

__global__ void cvt_f32_bf16(const float* __restrict__ src, unsigned short* __restrict__ dst, long n) {
  long i = (long)blockIdx.x * blockDim.x + threadIdx.x;
  long st = (long)gridDim.x * blockDim.x;
  for (; i < n; i += st) dst[i] = f2bf(src[i]);
}

// One block per timestep t: stage x[.][t][.] (64x512 -> bf16) in LDS once,
// then 4 waves sweep the 2048 gate rows (weights re-read from L2).
// xg[t][g][b] = sum_k x[b][t][k]*Wx0[g][k] + bx0[g] + bh0[g].
__global__ __launch_bounds__(256) void proj_kernel(
    const float* __restrict__ x,              // [B][T][D] f32
    const unsigned short* __restrict__ Wb,    // [2048][512] bf16
    const float* __restrict__ ba,             // bx0 [2048]
    const float* __restrict__ bb,             // bh0 [2048]
    unsigned short* __restrict__ xg) {
  __shared__ unsigned short xt[64 * 512];     // 64 KB, XOR-swizzled rows
  const int t   = blockIdx.x;
  const int tid = threadIdx.x;

  for (int i = 0; i < 16; ++i) {
    const int c    = i * 256 + tid;
    const int b    = c >> 6;
    const int col8 = c & 63;
    const float* src = x + ((long)b * T_STEPS + t) * DIN + col8 * 8;
    f32x4 v0 = *(const f32x4*)(src);
    f32x4 v1 = *(const f32x4*)(src + 4);
    union { unsigned short s[8]; bf16x8 v; } u;
    #pragma unroll
    for (int e = 0; e < 4; ++e) { u.s[e] = f2bf(v0[e]); u.s[4 + e] = f2bf(v1[e]); }
    const int byteoff = b * 1024 + ((col8 * 16) ^ ((b & 7) << 4));
    *(bf16x8*)((char*)xt + byteoff) = u.v;
  }
  __syncthreads();

  const int wv   = tid >> 6;
  const int lane = tid & 63;
  const int n16  = lane & 15;
  const int q    = lane >> 4;
  const int kof  = q * 8;

  for (int gt = 0; gt < 32; ++gt) {
    const int g0 = wv * 512 + gt * 16;
    const unsigned short* ap = Wb + (long)(g0 + n16) * DIN + kof;
    f32x4 acc[4];
    #pragma unroll
    for (int nb = 0; nb < 4; ++nb) acc[nb] = (f32x4){0.f, 0.f, 0.f, 0.f};
    #pragma unroll
    for (int kk = 0; kk < 16; ++kk) {
      bf16x8 a = *(const bf16x8*)(ap + kk * 32);
      const int colb = (kof + kk * 32) * 2;
      #pragma unroll
      for (int nb = 0; nb < 4; ++nb) {
        const int row = nb * 16 + n16;
        bf16x8 bv = *(const bf16x8*)((const char*)xt + row * 1024 + (colb ^ ((row & 7) << 4)));
        acc[nb] = __builtin_amdgcn_mfma_f32_16x16x32_bf16(a, bv, acc[nb], 0, 0, 0);
      }
    }
    const int m0 = q * 4;
    #pragma unroll
    for (int r = 0; r < 4; ++r) {
      const int g = g0 + m0 + r;
      const float bv = ba[g] + bb[g];
      long base = ((long)t * G4 + g) * BATCH + n16;
      xg[base +  0] = f2bf(acc[0][r] + bv);
      xg[base + 16] = f2bf(acc[1][r] + bv);
      xg[base + 32] = f2bf(acc[2][r] + bv);
      xg[base + 48] = f2bf(acc[3][r] + bv);
    }
  }
}

// Fused 2-layer dataflow recurrence (R6 structure, best measured: 1790us).
// 256 WGs x 128 threads, 1 WG/CU. Sentinel-polled T-deep h rings through L3
// (agent-scope), no flags, no fences, no drains. Weight LDS fill converts
// f32->bf16 inline. L1 polls serially (A then B) — pre-issuing both sets
// regresses (every A-retry vmcnt(0) drains B's outstanding loads; R8 data).
__global__ __launch_bounds__(128) void fused_rec(
    const float* __restrict__ Wh0,            // [2048][512] f32
    const float* __restrict__ Wx1,            // [2048][512] f32
    const float* __restrict__ Wh1,            // [2048][512] f32
    const float* __restrict__ bx1, const float* __restrict__ bh1,
    const unsigned short* __restrict__ xg0,   // [T][2048][64] bf16 (bias folded)
    unsigned short* __restrict__ hseq1,       // [T][64][4][16][8] bf16, 0xFF-filled
    unsigned short* __restrict__ hseq2,       // [T][64][4][16][8] bf16, 0xFF-filled
    float* __restrict__ out,                  // [64][512]
    int T) {
  __shared__ unsigned short whl0[32 * 512];    // 32 KB
  __shared__ unsigned short whl1[32 * 1024];   // 64 KB
  __shared__ __align__(16) unsigned short hsc[2][128];

  const int bid  = blockIdx.x;
  const int gq   = bid & 3;
  const int j    = bid >> 2;
  const int wv   = threadIdx.x >> 6;
  const int lane = threadIdx.x & 63;
  const int hidbase = j * 8;
  const int n16  = lane & 15;
  const int q    = lane >> 4;
  const int kof  = q * 8;
  const int bloc = q * 4;
  const int rr0 = n16, rr1 = 16 + n16;
  const int grow0 = (rr0 >> 3) * HID + hidbase + (rr0 & 7);
  const int grow1 = (rr1 >> 3) * HID + hidbase + (rr1 & 7);
  const int rdbase = gq * 128 + n16 * 8;       // ushort units
  const int myblk  = (j * 4 + gq) * 128;       // ushort units

  // ---- LDS weight fills (f32 -> bf16 inline, XOR-swizzled) ----
  auto cv8 = [](const float* s) -> bf16x8 {
    f32x4 a = *(const f32x4*)s, b = *(const f32x4*)(s + 4);
    union { unsigned short u[8]; bf16x8 v; } w;
    #pragma unroll
    for (int e = 0; e < 4; ++e) { w.u[e] = f2bf(a[e]); w.u[4 + e] = f2bf(b[e]); }
    return w.v;
  };
  if (wv == 0) {
    for (int r = 0; r < 32; ++r) {
      const long grow = (long)(r >> 3) * HID + hidbase + (r & 7);
      bf16x8 v = cv8(Wh0 + grow * HID + lane * 8);
      *(bf16x8*)((char*)whl0 + r * 1024 + ((lane * 16) ^ ((r & 7) << 4))) = v;
    }
  } else {
    for (int r = 0; r < 32; ++r) {
      const long grow = (long)(r >> 3) * HID + hidbase + (r & 7);
      bf16x8 va = cv8(Wx1 + grow * HID + lane * 8);
      bf16x8 vb = cv8(Wh1 + grow * HID + lane * 8);
      const int rb = r * 2048;
      *(bf16x8*)((char*)whl1 + rb + ((lane * 16) ^ ((r & 7) << 4))) = va;
      *(bf16x8*)((char*)whl1 + rb + ((1024 + lane * 16) ^ ((r & 7) << 4))) = vb;
    }
  }
  __syncthreads();  // once; the two waves decouple afterwards

  if (wv == 0) {
    // ================= layer 0 =================
    float c4[4] = {0.f, 0.f, 0.f, 0.f};
    for (int t = 0; t < T; ++t) {
      // xg slice: issue BEFORE the poll so the HBM miss hides under the wait
      us4 xv0 = *(const us4*)(xg0 + ((long)t * G4 + grow0) * BATCH + gq * 16 + bloc);
      us4 xv1 = *(const us4*)(xg0 + ((long)t * G4 + grow1) * BATCH + gq * 16 + bloc);

      f32x4 acc0 = {0.f,0.f,0.f,0.f}, acc1 = {0.f,0.f,0.f,0.f};
      if (t > 0) {
        const ull* hp = (const ull*)(hseq1 + (long)(t - 1) * HBLK_T + rdbase);
        ull lo[16], hi[16];
        int bad;
        do {
          bad = 0;
          #pragma unroll
          for (int kk = 0; kk < 16; ++kk) {
            const int boff = (kk * 4 + q) * 128;
            lo[kk] = AGLD(hp + boff);
            hi[kk] = AGLD(hp + boff + 1);
          }
          #pragma unroll
          for (int kk = 0; kk < 16; ++kk)
            bad |= (lo[kk] == SENT8) | (hi[kk] == SENT8);
        } while (__any(bad));
        #pragma unroll
        for (int kk = 0; kk < 16; ++kk) {
          union { ull qq[2]; bf16x8 v; } u; u.qq[0] = lo[kk]; u.qq[1] = hi[kk];
          const int colb = (kof + kk * 32) * 2;
          bf16x8 b0 = *(const bf16x8*)((const char*)whl0 + rr0 * 1024 + (colb ^ ((rr0 & 7) << 4)));
          bf16x8 b1 = *(const bf16x8*)((const char*)whl0 + rr1 * 1024 + (colb ^ ((rr1 & 7) << 4)));
          acc0 = __builtin_amdgcn_mfma_f32_16x16x32_bf16(u.v, b0, acc0, 0, 0, 0);
          acc1 = __builtin_amdgcn_mfma_f32_16x16x32_bf16(u.v, b1, acc1, 0, 0, 0);
        }
      }
      #pragma unroll
      for (int r = 0; r < 4; ++r) { acc0[r] += bf2f(xv0[r]); acc1[r] += bf2f(xv1[r]); }

      f32x4 o0, o1;
      #pragma unroll
      for (int r = 0; r < 4; ++r) {
        o0[r] = __shfl_xor(acc0[r], 8, 64);
        o1[r] = __shfl_xor(acc1[r], 8, 64);
      }
      if (n16 < 8) {
        #pragma unroll
        for (int r = 0; r < 4; ++r) {
          const float fg = sigf(acc0[r]);
          const float ig = sigf(o0[r]);
          const float gg = tanh_fast(acc1[r]);
          const float og = sigf(o1[r]);
          const float cn = fg * c4[r] + ig * gg;
          c4[r] = cn;
          const float h = og * tanh_fast(cn);
          *(unsigned short*)((char*)hsc[0] + (bloc + r) * 16 + n16 * 2) = f2bf(h);
        }
      }
      asm volatile("s_waitcnt lgkmcnt(0)" ::: "memory");
      if (lane < 32) {  // 4 full 64B lines; consumers poll for arrival
        ull v8 = *(const ull*)((const char*)hsc[0] + lane * 8);
        ull* dst = (ull*)(hseq1 + (long)t * HBLK_T + myblk) + lane;
        AGST(dst, v8);
      }
      // no drain, no flag
    }
  } else {
    // ================= layer 1 =================
    float c4[4] = {0.f, 0.f, 0.f, 0.f};
    const float b0v = bx1[grow0] + bh1[grow0];
    const float b1v = bx1[grow1] + bh1[grow1];
    for (int t = 0; t < T; ++t) {
      f32x4 acc0 = {0.f,0.f,0.f,0.f}, acc1 = {0.f,0.f,0.f,0.f};
      // ---- part A: Wx1 * h1[t] (poll hseq1[t]) ----
      {
        const ull* hp = (const ull*)(hseq1 + (long)t * HBLK_T + rdbase);
        ull lo[16], hi[16];
        int bad;
        do {
          bad = 0;
          #pragma unroll
          for (int kk = 0; kk < 16; ++kk) {
            const int boff = (kk * 4 + q) * 128;
            lo[kk] = AGLD(hp + boff);
            hi[kk] = AGLD(hp + boff + 1);
          }
          #pragma unroll
          for (int kk = 0; kk < 16; ++kk)
            bad |= (lo[kk] == SENT8) | (hi[kk] == SENT8);
        } while (__any(bad));
        #pragma unroll
        for (int kk = 0; kk < 16; ++kk) {
          union { ull qq[2]; bf16x8 v; } u; u.qq[0] = lo[kk]; u.qq[1] = hi[kk];
          const int colb = (kof + kk * 32) * 2;
          bf16x8 b0 = *(const bf16x8*)((const char*)whl1 + rr0 * 2048 + (colb ^ ((rr0 & 7) << 4)));
          bf16x8 b1 = *(const bf16x8*)((const char*)whl1 + rr1 * 2048 + (colb ^ ((rr1 & 7) << 4)));
          acc0 = __builtin_amdgcn_mfma_f32_16x16x32_bf16(u.v, b0, acc0, 0, 0, 0);
          acc1 = __builtin_amdgcn_mfma_f32_16x16x32_bf16(u.v, b1, acc1, 0, 0, 0);
        }
      }
      // ---- part B: Wh1 * h2[t-1] (poll hseq2[t-1]) ----
      if (t > 0) {
        const ull* hp = (const ull*)(hseq2 + (long)(t - 1) * HBLK_T + rdbase);
        ull lo[16], hi[16];
        int bad;
        do {
          bad = 0;
          #pragma unroll
          for (int kk = 0; kk < 16; ++kk) {
            const int boff = (kk * 4 + q) * 128;
            lo[kk] = AGLD(hp + boff);
            hi[kk] = AGLD(hp + boff + 1);
          }
          #pragma unroll
          for (int kk = 0; kk < 16; ++kk)
            bad |= (lo[kk] == SENT8) | (hi[kk] == SENT8);
        } while (__any(bad));
        #pragma unroll
        for (int kk = 0; kk < 16; ++kk) {
          union { ull qq[2]; bf16x8 v; } u; u.qq[0] = lo[kk]; u.qq[1] = hi[kk];
          const int colb = 1024 + (kof + kk * 32) * 2;
          bf16x8 b0 = *(const bf16x8*)((const char*)whl1 + rr0 * 2048 + (colb ^ ((rr0 & 7) << 4)));
          bf16x8 b1 = *(const bf16x8*)((const char*)whl1 + rr1 * 2048 + (colb ^ ((rr1 & 7) << 4)));
          acc0 = __builtin_amdgcn_mfma_f32_16x16x32_bf16(u.v, b0, acc0, 0, 0, 0);
          acc1 = __builtin_amdgcn_mfma_f32_16x16x32_bf16(u.v, b1, acc1, 0, 0, 0);
        }
      }
      #pragma unroll
      for (int r = 0; r < 4; ++r) { acc0[r] += b0v; acc1[r] += b1v; }

      f32x4 o0, o1;
      #pragma unroll
      for (int r = 0; r < 4; ++r) {
        o0[r] = __shfl_xor(acc0[r], 8, 64);
        o1[r] = __shfl_xor(acc1[r], 8, 64);
      }
      if (n16 < 8) {
        const int hid = hidbase + n16;
        #pragma unroll
        for (int r = 0; r < 4; ++r) {
          const float fg = sigf(acc0[r]);
          const float ig = sigf(o0[r]);
          const float gg = tanh_fast(acc1[r]);
          const float og = sigf(o1[r]);
          const float cn = fg * c4[r] + ig * gg;
          c4[r] = cn;
          const float h = og * tanh_fast(cn);
          *(unsigned short*)((char*)hsc[1] + (bloc + r) * 16 + n16 * 2) = f2bf(h);
          if (t == T - 1) out[(long)(gq * 16 + bloc + r) * HID + hid] = h;
        }
      }
      asm volatile("s_waitcnt lgkmcnt(0)" ::: "memory");
      if (lane < 32) {
        ull v8 = *(const ull*)((const char*)hsc[1] + lane * 8);
        ull* dst = (ull*)(hseq2 + (long)t * HBLK_T + myblk) + lane;
        AGST(dst, v8);
      }
    }
  }
}

extern "C" void kernel_launch(void* const* d_in, const int* in_sizes, int n_in,
                              void* d_out, int out_size, void* d_ws, size_t ws_size,
                              hipStream_t stream) {
  const float* x   = (const float*)d_in[0];
  const float* Wx0 = (const float*)d_in[1];
  const float* bx0 = (const float*)d_in[2];
  const float* Wh0 = (const float*)d_in[3];
  const float* bh0 = (const float*)d_in[4];
  const float* Wx1 = (const float*)d_in[5];
  const float* bx1 = (const float*)d_in[6];
  const float* Wh1 = (const float*)d_in[7];
  const float* bh1 = (const float*)d_in[8];

  char* ws = (char*)d_ws;
  size_t off = 0;
  auto alloc = [&](size_t bytes) -> char* {
    char* p = ws + off; off += (bytes + 255) & ~(size_t)255; return p;
  };
  unsigned short* xg    = (unsigned short*)alloc((size_t)T_STEPS * G4 * BATCH * 2);  // 128 MiB
  unsigned short* hseq1 = (unsigned short*)alloc((size_t)T_STEPS * HBLK_T * 2);      // 32 MiB
  unsigned short* hseq2 = (unsigned short*)alloc((size_t)T_STEPS * HBLK_T * 2);      // 32 MiB
  unsigned short* Wx0b  = (unsigned short*)alloc((size_t)G4 * DIN * 2);              // 2 MiB

  // sentinel-fill the h rings (0xFF bytes = bf16 -NaN, unreachable for real h)
  hipMemsetAsync(hseq1, 0xFF, (size_t)T_STEPS * HBLK_T * 2, stream);
  hipMemsetAsync(hseq2, 0xFF, (size_t)T_STEPS * HBLK_T * 2, stream);

  cvt_f32_bf16<<<1024, 256, 0, stream>>>(Wx0, Wx0b, (long)G4 * DIN);

  // layer-0 input projections: one block per timestep, x staged+converted in LDS
  proj_kernel<<<T_STEPS, 256, 0, stream>>>(x, Wx0b, bx0, bh0, xg);
  // fused dataflow 2-layer recurrence (R6 structure)
  fused_rec<<<256, 128, 0, stream>>>(Wh0, Wx1, Wh1, bx1, bh1,
                                     xg, hseq1, hseq2, (float*)d_out, T_STEPS);
}

// Round 16
// 2002.119 us; speedup vs baseline: 1.0472x; 1.0016x over previous
//
#include <hip/hip_runtime.h>
#include <hip/hip_bf16.h>
#include <stdint.h>

#define T_STEPS 512
#define BATCH   64
#define HID     512
#define DIN     512
#define G4      2048   // 4*HID
// blocked h layout: [t][j=64][gq=4][b=16][h=8] ushorts; per-t stride:
#define HBLK_T  32768  // ushorts (65536 bytes)
#define SENT8   0xFFFFFFFFFFFFFFFFull   // 4x bf16 0xFFFF (-NaN): unreachable for finite h

typedef __attribute__((ext_vector_type(8))) short bf16x8;
typedef __attribute__((ext_vector_type(4))) float f32x4;
typedef __attribute__((ext_vector_type(4))) unsigned short us4;
typedef unsigned long long ull;

#define AGLD(p) __hip_atomic_load((p), __ATOMIC_RELAXED, __HIP_MEMORY_SCOPE_AGENT)
#define AGST(p, v) __hip_atomic_store((p), (v), __ATOMIC_RELAXED, __HIP_MEMORY_SCOPE_AGENT)

static __device__ __forceinline__ unsigned short f2bf(float f) {
  union { float f; unsigned u; } v; v.f = f;
  unsigned r = v.u + 0x7FFFu + ((v.u >> 16) & 1u);  // round-to-nearest-even
  return (unsigned short)(r >> 16);
}
static __device__ __forceinline__ float bf2f(unsigned short s) {
  union { unsigned u; float f; } v; v.u = ((unsigned)s) << 16;
  return v.f;
}
static __device__ __forceinline__ float sigf(float x) { return 1.f / (1.f + __expf(-x)); }
static __device__ __forceinline__ float tanh_fast(float x) {
  x = fminf(15.f, fmaxf(-15.f, x));
  float e = __expf(2.f * x);
  return (e - 1.f) / (e + 1.f);
}

__global__ void cvt_f32_bf16(const float* __restrict__ src, unsigned short* __restrict__ dst, long n) {
  long i = (long)blockIdx.x * blockDim.x + threadIdx.x;
  long st = (long)gridDim.x * blockDim.x;
  for (; i < n; i += st) dst[i] = f2bf(src[i]);
}

// One block per timestep t: stage x[.][t][.] (64x512 -> bf16) in LDS once,
// then 4 waves sweep the 2048 gate rows (weights re-read from L2).
// xg[t][g][b] = sum_k x[b][t][k]*Wx0[g][k] + bx0[g] + bh0[g].
__global__ __launch_bounds__(256) void proj_kernel(
    const float* __restrict__ x,              // [B][T][D] f32
    const unsigned short* __restrict__ Wb,    // [2048][512] bf16
    const float* __restrict__ ba,             // bx0 [2048]
    const float* __restrict__ bb,             // bh0 [2048]
    unsigned short* __restrict__ xg) {
  __shared__ unsigned short xt[64 * 512];     // 64 KB, XOR-swizzled rows
  const int t   = blockIdx.x;
  const int tid = threadIdx.x;

  for (int i = 0; i < 16; ++i) {
    const int c    = i * 256 + tid;
    const int b    = c >> 6;
    const int col8 = c & 63;
    const float* src = x + ((long)b * T_STEPS + t) * DIN + col8 * 8;
    f32x4 v0 = *(const f32x4*)(src);
    f32x4 v1 = *(const f32x4*)(src + 4);
    union { unsigned short s[8]; bf16x8 v; } u;
    #pragma unroll
    for (int e = 0; e < 4; ++e) { u.s[e] = f2bf(v0[e]); u.s[4 + e] = f2bf(v1[e]); }
    const int byteoff = b * 1024 + ((col8 * 16) ^ ((b & 7) << 4));
    *(bf16x8*)((char*)xt + byteoff) = u.v;
  }
  __syncthreads();

  const int wv   = tid >> 6;
  const int lane = tid & 63;
  const int n16  = lane & 15;
  const int q    = lane >> 4;
  const int kof  = q * 8;

  for (int gt = 0; gt < 32; ++gt) {
    const int g0 = wv * 512 + gt * 16;
    const unsigned short* ap = Wb + (long)(g0 + n16) * DIN + kof;
    f32x4 acc[4];
    #pragma unroll
    for (int nb = 0; nb < 4; ++nb) acc[nb] = (f32x4){0.f, 0.f, 0.f, 0.f};
    #pragma unroll
    for (int kk = 0; kk < 16; ++kk) {
      bf16x8 a = *(const bf16x8*)(ap + kk * 32);
      const int colb = (kof + kk * 32) * 2;
      #pragma unroll
      for (int nb = 0; nb < 4; ++nb) {
        const int row = nb * 16 + n16;
        bf16x8 bv = *(const bf16x8*)((const char*)xt + row * 1024 + (colb ^ ((row & 7) << 4)));
        acc[nb] = __builtin_amdgcn_mfma_f32_16x16x32_bf16(a, bv, acc[nb], 0, 0, 0);
      }
    }
    const int m0 = q * 4;
    #pragma unroll
    for (int r = 0; r < 4; ++r) {
      const int g = g0 + m0 + r;
      const float bv = ba[g] + bb[g];
      long base = ((long)t * G4 + g) * BATCH + n16;
      xg[base +  0] = f2bf(acc[0][r] + bv);
      xg[base + 16] = f2bf(acc[1][r] + bv);
      xg[base + 32] = f2bf(acc[2][r] + bv);
      xg[base + 48] = f2bf(acc[3][r] + bv);
    }
  }
}

// Fused 2-layer dataflow recurrence (R6/R13 structure — best measured passing
// configuration). 256 WGs x 128 threads, 1 WG/CU. Sentinel-polled T-deep h
// rings through L3 via 8B agent-scope atomics (the ONLY exchange width that
// validates: plain 16B vector ops tear/miscohere — R12/R14/R15 all failed).
// No flags, no fences, no drains.
__global__ __launch_bounds__(128) void fused_rec(
    const float* __restrict__ Wh0,            // [2048][512] f32
    const float* __restrict__ Wx1,            // [2048][512] f32
    const float* __restrict__ Wh1,            // [2048][512] f32
    const float* __restrict__ bx1, const float* __restrict__ bh1,
    const unsigned short* __restrict__ xg0,   // [T][2048][64] bf16 (bias folded)
    unsigned short* __restrict__ hseq1,       // [T][64][4][16][8] bf16, 0xFF-filled
    unsigned short* __restrict__ hseq2,       // [T][64][4][16][8] bf16, 0xFF-filled
    float* __restrict__ out,                  // [64][512]
    int T) {
  __shared__ unsigned short whl0[32 * 512];    // 32 KB
  __shared__ unsigned short whl1[32 * 1024];   // 64 KB
  __shared__ __align__(16) unsigned short hsc[2][128];

  const int bid  = blockIdx.x;
  const int gq   = bid & 3;
  const int j    = bid >> 2;
  const int wv   = threadIdx.x >> 6;
  const int lane = threadIdx.x & 63;
  const int hidbase = j * 8;
  const int n16  = lane & 15;
  const int q    = lane >> 4;
  const int kof  = q * 8;
  const int bloc = q * 4;
  const int rr0 = n16, rr1 = 16 + n16;
  const int grow0 = (rr0 >> 3) * HID + hidbase + (rr0 & 7);
  const int grow1 = (rr1 >> 3) * HID + hidbase + (rr1 & 7);
  const int rdbase = gq * 128 + n16 * 8;       // ushort units
  const int myblk  = (j * 4 + gq) * 128;       // ushort units

  // ---- LDS weight fills (f32 -> bf16 inline, XOR-swizzled) ----
  auto cv8 = [](const float* s) -> bf16x8 {
    f32x4 a = *(const f32x4*)s, b = *(const f32x4*)(s + 4);
    union { unsigned short u[8]; bf16x8 v; } w;
    #pragma unroll
    for (int e = 0; e < 4; ++e) { w.u[e] = f2bf(a[e]); w.u[4 + e] = f2bf(b[e]); }
    return w.v;
  };
  if (wv == 0) {
    for (int r = 0; r < 32; ++r) {
      const long grow = (long)(r >> 3) * HID + hidbase + (r & 7);
      bf16x8 v = cv8(Wh0 + grow * HID + lane * 8);
      *(bf16x8*)((char*)whl0 + r * 1024 + ((lane * 16) ^ ((r & 7) << 4))) = v;
    }
  } else {
    for (int r = 0; r < 32; ++r) {
      const long grow = (long)(r >> 3) * HID + hidbase + (r & 7);
      bf16x8 va = cv8(Wx1 + grow * HID + lane * 8);
      bf16x8 vb = cv8(Wh1 + grow * HID + lane * 8);
      const int rb = r * 2048;
      *(bf16x8*)((char*)whl1 + rb + ((lane * 16) ^ ((r & 7) << 4))) = va;
      *(bf16x8*)((char*)whl1 + rb + ((1024 + lane * 16) ^ ((r & 7) << 4))) = vb;
    }
  }
  __syncthreads();  // once; the two waves decouple afterwards

  if (wv == 0) {
    // ================= layer 0 =================
    float c4[4] = {0.f, 0.f, 0.f, 0.f};
    for (int t = 0; t < T; ++t) {
      // xg slice: issue BEFORE the poll so the HBM miss hides under the wait
      us4 xv0 = *(const us4*)(xg0 + ((long)t * G4 + grow0) * BATCH + gq * 16 + bloc);
      us4 xv1 = *(const us4*)(xg0 + ((long)t * G4 + grow1) * BATCH + gq * 16 + bloc);

      f32x4 acc0 = {0.f,0.f,0.f,0.f}, acc1 = {0.f,0.f,0.f,0.f};
      if (t > 0) {
        const ull* hp = (const ull*)(hseq1 + (long)(t - 1) * HBLK_T + rdbase);
        ull lo[16], hi[16];
        int bad;
        do {
          bad = 0;
          #pragma unroll
          for (int kk = 0; kk < 16; ++kk) {
            const int boff = (kk * 4 + q) * 128;
            lo[kk] = AGLD(hp + boff);
            hi[kk] = AGLD(hp + boff + 1);
          }
          #pragma unroll
          for (int kk = 0; kk < 16; ++kk)
            bad |= (lo[kk] == SENT8) | (hi[kk] == SENT8);
        } while (__any(bad));
        #pragma unroll
        for (int kk = 0; kk < 16; ++kk) {
          union { ull qq[2]; bf16x8 v; } u; u.qq[0] = lo[kk]; u.qq[1] = hi[kk];
          const int colb = (kof + kk * 32) * 2;
          bf16x8 b0 = *(const bf16x8*)((const char*)whl0 + rr0 * 1024 + (colb ^ ((rr0 & 7) << 4)));
          bf16x8 b1 = *(const bf16x8*)((const char*)whl0 + rr1 * 1024 + (colb ^ ((rr1 & 7) << 4)));
          acc0 = __builtin_amdgcn_mfma_f32_16x16x32_bf16(u.v, b0, acc0, 0, 0, 0);
          acc1 = __builtin_amdgcn_mfma_f32_16x16x32_bf16(u.v, b1, acc1, 0, 0, 0);
        }
      }
      #pragma unroll
      for (int r = 0; r < 4; ++r) { acc0[r] += bf2f(xv0[r]); acc1[r] += bf2f(xv1[r]); }

      f32x4 o0, o1;
      #pragma unroll
      for (int r = 0; r < 4; ++r) {
        o0[r] = __shfl_xor(acc0[r], 8, 64);
        o1[r] = __shfl_xor(acc1[r], 8, 64);
      }
      if (n16 < 8) {
        #pragma unroll
        for (int r = 0; r < 4; ++r) {
          const float fg = sigf(acc0[r]);
          const float ig = sigf(o0[r]);
          const float gg = tanh_fast(acc1[r]);
          const float og = sigf(o1[r]);
          const float cn = fg * c4[r] + ig * gg;
          c4[r] = cn;
          const float h = og * tanh_fast(cn);
          *(unsigned short*)((char*)hsc[0] + (bloc + r) * 16 + n16 * 2) = f2bf(h);
        }
      }
      asm volatile("s_waitcnt lgkmcnt(0)" ::: "memory");
      if (lane < 32) {  // 4 full 64B lines; consumers poll for arrival
        ull v8 = *(const ull*)((const char*)hsc[0] + lane * 8);
        ull* dst = (ull*)(hseq1 + (long)t * HBLK_T + myblk) + lane;
        AGST(dst, v8);
      }
      // no drain, no flag
    }
  } else {
    // ================= layer 1 =================
    float c4[4] = {0.f, 0.f, 0.f, 0.f};
    const float b0v = bx1[grow0] + bh1[grow0];
    const float b1v = bx1[grow1] + bh1[grow1];
    for (int t = 0; t < T; ++t) {
      f32x4 acc0 = {0.f,0.f,0.f,0.f}, acc1 = {0.f,0.f,0.f,0.f};
      // ---- part A: Wx1 * h1[t] (poll hseq1[t]) ----
      {
        const ull* hp = (const ull*)(hseq1 + (long)t * HBLK_T + rdbase);
        ull lo[16], hi[16];
        int bad;
        do {
          bad = 0;
          #pragma unroll
          for (int kk = 0; kk < 16; ++kk) {
            const int boff = (kk * 4 + q) * 128;
            lo[kk] = AGLD(hp + boff);
            hi[kk] = AGLD(hp + boff + 1);
          }
          #pragma unroll
          for (int kk = 0; kk < 16; ++kk)
            bad |= (lo[kk] == SENT8) | (hi[kk] == SENT8);
        } while (__any(bad));
        #pragma unroll
        for (int kk = 0; kk < 16; ++kk) {
          union { ull qq[2]; bf16x8 v; } u; u.qq[0] = lo[kk]; u.qq[1] = hi[kk];
          const int colb = (kof + kk * 32) * 2;
          bf16x8 b0 = *(const bf16x8*)((const char*)whl1 + rr0 * 2048 + (colb ^ ((rr0 & 7) << 4)));
          bf16x8 b1 = *(const bf16x8*)((const char*)whl1 + rr1 * 2048 + (colb ^ ((rr1 & 7) << 4)));
          acc0 = __builtin_amdgcn_mfma_f32_16x16x32_bf16(u.v, b0, acc0, 0, 0, 0);
          acc1 = __builtin_amdgcn_mfma_f32_16x16x32_bf16(u.v, b1, acc1, 0, 0, 0);
        }
      }
      // ---- part B: Wh1 * h2[t-1] (poll hseq2[t-1]) ----
      if (t > 0) {
        const ull* hp = (const ull*)(hseq2 + (long)(t - 1) * HBLK_T + rdbase);
        ull lo[16], hi[16];
        int bad;
        do {
          bad = 0;
          #pragma unroll
          for (int kk = 0; kk < 16; ++kk) {
            const int boff = (kk * 4 + q) * 128;
            lo[kk] = AGLD(hp + boff);
            hi[kk] = AGLD(hp + boff + 1);
          }
          #pragma unroll
          for (int kk = 0; kk < 16; ++kk)
            bad |= (lo[kk] == SENT8) | (hi[kk] == SENT8);
        } while (__any(bad));
        #pragma unroll
        for (int kk = 0; kk < 16; ++kk) {
          union { ull qq[2]; bf16x8 v; } u; u.qq[0] = lo[kk]; u.qq[1] = hi[kk];
          const int colb = 1024 + (kof + kk * 32) * 2;
          bf16x8 b0 = *(const bf16x8*)((const char*)whl1 + rr0 * 2048 + (colb ^ ((rr0 & 7) << 4)));
          bf16x8 b1 = *(const bf16x8*)((const char*)whl1 + rr1 * 2048 + (colb ^ ((rr1 & 7) << 4)));
          acc0 = __builtin_amdgcn_mfma_f32_16x16x32_bf16(u.v, b0, acc0, 0, 0, 0);
          acc1 = __builtin_amdgcn_mfma_f32_16x16x32_bf16(u.v, b1, acc1, 0, 0, 0);
        }
      }
      #pragma unroll
      for (int r = 0; r < 4; ++r) { acc0[r] += b0v; acc1[r] += b1v; }

      f32x4 o0, o1;
      #pragma unroll
      for (int r = 0; r < 4; ++r) {
        o0[r] = __shfl_xor(acc0[r], 8, 64);
        o1[r] = __shfl_xor(acc1[r], 8, 64);
      }
      if (n16 < 8) {
        const int hid = hidbase + n16;
        #pragma unroll
        for (int r = 0; r < 4; ++r) {
          const float fg = sigf(acc0[r]);
          const float ig = sigf(o0[r]);
          const float gg = tanh_fast(acc1[r]);
          const float og = sigf(o1[r]);
          const float cn = fg * c4[r] + ig * gg;
          c4[r] = cn;
          const float h = og * tanh_fast(cn);
          *(unsigned short*)((char*)hsc[1] + (bloc + r) * 16 + n16 * 2) = f2bf(h);
          if (t == T - 1) out[(long)(gq * 16 + bloc + r) * HID + hid] = h;
        }
      }
      asm volatile("s_waitcnt lgkmcnt(0)" ::: "memory");
      if (lane < 32) {
        ull v8 = *(const ull*)((const char*)hsc[1] + lane * 8);
        ull* dst = (ull*)(hseq2 + (long)t * HBLK_T + myblk) + lane;
        AGST(dst, v8);
      }
    }
  }
}

extern "C" void kernel_launch(void* const* d_in, const int* in_sizes, int n_in,
                              void* d_out, int out_size, void* d_ws, size_t ws_size,
                              hipStream_t stream) {
  const float* x   = (const float*)d_in[0];
  const float* Wx0 = (const float*)d_in[1];
  const float* bx0 = (const float*)d_in[2];
  const float* Wh0 = (const float*)d_in[3];
  const float* bh0 = (const float*)d_in[4];
  const float* Wx1 = (const float*)d_in[5];
  const float* bx1 = (const float*)d_in[6];
  const float* Wh1 = (const float*)d_in[7];
  const float* bh1 = (const float*)d_in[8];

  char* ws = (char*)d_ws;
  size_t off = 0;
  auto alloc = [&](size_t bytes) -> char* {
    char* p = ws + off; off += (bytes + 255) & ~(size_t)255; return p;
  };
  unsigned short* xg    = (unsigned short*)alloc((size_t)T_STEPS * G4 * BATCH * 2);  // 128 MiB
  unsigned short* hseq1 = (unsigned short*)alloc((size_t)T_STEPS * HBLK_T * 2);      // 32 MiB
  unsigned short* hseq2 = (unsigned short*)alloc((size_t)T_STEPS * HBLK_T * 2);      // 32 MiB
  unsigned short* Wx0b  = (unsigned short*)alloc((size_t)G4 * DIN * 2);              // 2 MiB

  // sentinel-fill the h rings (0xFF bytes = bf16 -NaN, unreachable for real h)
  hipMemsetAsync(hseq1, 0xFF, (size_t)T_STEPS * HBLK_T * 2, stream);
  hipMemsetAsync(hseq2, 0xFF, (size_t)T_STEPS * HBLK_T * 2, stream);

  cvt_f32_bf16<<<1024, 256, 0, stream>>>(Wx0, Wx0b, (long)G4 * DIN);

  // layer-0 input projections: one block per timestep, x staged+converted in LDS
  proj_kernel<<<T_STEPS, 256, 0, stream>>>(x, Wx0b, bx0, bh0, xg);
  // fused dataflow 2-layer recurrence (R6/R13 structure, 8B atomic exchange)
  fused_rec<<<256, 128, 0, stream>>>(Wh0, Wx1, Wh1, bx1, bh1,
                                     xg, hseq1, hseq2, (float*)d_out, T_STEPS);
}